// Round 11
// baseline (179.622 us; speedup 1.0000x reference)
//
#include <hip/hip_runtime.h>
#include <math.h>

#define NTOK 384
#define DIM  128
#define HEADS 4
#define DHEAD 64
#define INNER 256
#define DEPTH 3
#define EDGE 8
#define FFD 512

__device__ __forceinline__ float wave_sum64(float v){
#pragma unroll
  for (int m = 32; m >= 1; m >>= 1) v += __shfl_xor(v, m, 64);
  return v;
}
__device__ __forceinline__ float wave_max64(float v){
#pragma unroll
  for (int m = 32; m >= 1; m >>= 1) v = fmaxf(v, __shfl_xor(v, m, 64));
  return v;
}

// XCD-pinned row mapping: 384 = 8 XCDs x 48 rows.
__device__ __forceinline__ int swz_row(int id){ return (id & 7) * 48 + (id >> 3); }

// Rotary for one (i, d): numpy float32 semantics via double precision then round.
__device__ __forceinline__ void rotary_val(int i, int d, float* c, float* s){
  int j = d >> 1;
  double ex = (double)(2 * j) / 64.0;
  float p = (float)pow(10000.0, ex);
  float inv = 1.0f / p;
  float f = (float)i * inv;
  double fd = (double)f;
  *c = (float)cos(fd);
  *s = (float)sin(fd);
}

// QKV (+rotary, qWe, qbe) for ONE row. Block >= 512 threads.
// t<192 -> (quad=t, ks=0); 192<=t<384 -> (quad=t-192, ks=1).
// quad 0-63: q col-quad; 64-127: k (transposed store); 128-191: v (transposed store).
// Contains 1 barrier (all threads reach it).
__device__ __forceinline__ void qkv_row_v2(
    int i, int t, const float* __restrict__ snx,
    const float* __restrict__ Wq, const float* __restrict__ bq,
    const float* __restrict__ Wkv, const float* __restrict__ bkv,
    const float* __restrict__ We, const float* __restrict__ be,
    const float* __restrict__ cosRow, const float* __restrict__ sinRow,
    float* __restrict__ qb_, float* __restrict__ kbT, float* __restrict__ vbT,
    float* __restrict__ qWeB, float* __restrict__ qbeB,
    float4* __restrict__ qp4)     // LDS, 192 float4
{
  int ks   = (t < 192) ? 0 : 1;
  int quad = (t < 192) ? t : t - 192;
  float4 acc = {0.f, 0.f, 0.f, 0.f};
  if (t < 384){
    const float4* Wp; int stride4;
    if (quad < 64){ Wp = (const float4*)Wq + quad;         stride4 = 64;  }
    else          { Wp = (const float4*)Wkv + (quad - 64); stride4 = 128; }
    int k0 = ks * 64;
#pragma unroll 8
    for (int kk = 0; kk < 64; ++kk){
      int k = k0 + kk;
      float4 w = Wp[(size_t)k * stride4];
      float x = snx[k];
      acc.x = fmaf(x, w.x, acc.x); acc.y = fmaf(x, w.y, acc.y);
      acc.z = fmaf(x, w.z, acc.z); acc.w = fmaf(x, w.w, acc.w);
    }
    if (ks == 1) qp4[quad] = acc;
  }
  __syncthreads();
  if (t < 192){
    float4 p = qp4[quad];
    acc.x += p.x; acc.y += p.y; acc.z += p.z; acc.w += p.w;
    if (quad < 64){
      int c0 = 4 * quad;
      float4 b = ((const float4*)bq)[quad];
      float a0 = acc.x + b.x, a1 = acc.y + b.y, a2 = acc.z + b.z, a3 = acc.w + b.w;
      int d0 = c0 & 63;
      float c_0 = cosRow[d0],     s_0 = sinRow[d0];
      float c_1 = cosRow[d0 + 2], s_1 = sinRow[d0 + 2];
      float r0 = a0 * c_0 - a1 * s_0;
      float r1 = a1 * c_0 + a0 * s_0;
      float r2 = a2 * c_1 - a3 * s_1;
      float r3 = a3 * c_1 + a2 * s_1;
      float4 qv; qv.x = r0; qv.y = r1; qv.z = r2; qv.w = r3;
      *(float4*)(qb_ + (size_t)i * 256 + c0) = qv;
      int h = quad >> 4;
#pragma unroll
      for (int cc = 0; cc < 8; ++cc){
        const float* wc = We + cc * 256 + c0;
        float pr = r0 * wc[0] + r1 * wc[1] + r2 * wc[2] + r3 * wc[3];
#pragma unroll
        for (int m = 8; m >= 1; m >>= 1) pr += __shfl_xor(pr, m, 16);
        if ((t & 15) == 0) qWeB[(h * NTOK + i) * 8 + cc] = pr;
      }
      const float* bc = be + c0;
      float pb = r0 * bc[0] + r1 * bc[1] + r2 * bc[2] + r3 * bc[3];
#pragma unroll
      for (int m = 8; m >= 1; m >>= 1) pb += __shfl_xor(pb, m, 16);
      if ((t & 15) == 0) qbeB[h * NTOK + i] = pb;
    } else if (quad < 128){
      int c0 = 4 * (quad - 64);
      float4 b = ((const float4*)bkv)[quad - 64];
      float a0 = acc.x + b.x, a1 = acc.y + b.y, a2 = acc.z + b.z, a3 = acc.w + b.w;
      int d0 = c0 & 63, h = c0 >> 6;
      float c_0 = cosRow[d0],     s_0 = sinRow[d0];
      float c_1 = cosRow[d0 + 2], s_1 = sinRow[d0 + 2];
      float r0 = a0 * c_0 - a1 * s_0;
      float r1 = a1 * c_0 + a0 * s_0;
      float r2 = a2 * c_1 - a3 * s_1;
      float r3 = a3 * c_1 + a2 * s_1;
      float* kp = kbT + (size_t)(h * 64 + d0) * NTOK + i;
      kp[0]        = r0;
      kp[NTOK]     = r1;
      kp[2 * NTOK] = r2;
      kp[3 * NTOK] = r3;
    } else {
      int vq = quad - 128;
      int c0 = 4 * vq;
      float4 b = ((const float4*)bkv)[64 + vq];
      float a0 = acc.x + b.x, a1 = acc.y + b.y, a2 = acc.z + b.z, a3 = acc.w + b.w;
      int d0 = c0 & 63, h = c0 >> 6;
      float* vp = vbT + (size_t)(h * 64 + d0) * NTOK + i;
      vp[0]        = a0;
      vp[NTOK]     = a1;
      vp[2 * NTOK] = a2;
      vp[3 * NTOK] = a3;
    }
  }
}

// Layer-0: rotary + LN1 (single wave) + QKV. 512 thr/row.
__global__ __launch_bounds__(512) void k_lnqkv(
    const float* __restrict__ x,
    const float* __restrict__ ls, const float* __restrict__ lb,
    const float* __restrict__ Wq, const float* __restrict__ bq,
    const float* __restrict__ Wkv, const float* __restrict__ bkv,
    const float* __restrict__ We, const float* __restrict__ be,
    float* __restrict__ cosS, float* __restrict__ sinS,
    float* __restrict__ qb_, float* __restrict__ kbT, float* __restrict__ vbT,
    float* __restrict__ qWeB, float* __restrict__ qbeB)
{
  __shared__ float snx[128];
  __shared__ float crow[64], srow[64];
  __shared__ float4 qp4[192];
  int i = swz_row(blockIdx.x);
  int t = threadIdx.x;

  if (t >= 448){
    int d = t - 448;
    float c, s;
    rotary_val(i, d, &c, &s);
    crow[d] = c; srow[d] = s;
    cosS[i * 64 + d] = c; sinS[i * 64 + d] = s;
  }
  if (t < 64){
    float x0 = x[(size_t)i * 128 + t], x1 = x[(size_t)i * 128 + 64 + t];
    float mu = wave_sum64(x0 + x1) * (1.0f / 128.0f);
    float d0 = x0 - mu, d1 = x1 - mu;
    float var = wave_sum64(d0 * d0 + d1 * d1) * (1.0f / 128.0f);
    float rstd = 1.0f / sqrtf(var + 1e-3f);
    snx[t]      = d0 * rstd * ls[t]      + lb[t];
    snx[t + 64] = d1 * rstd * ls[t + 64] + lb[t + 64];
  }
  __syncthreads();
  qkv_row_v2(i, t, snx, Wq, bq, Wkv, bkv, We, be, crow, srow,
             qb_, kbT, vbT, qWeB, qbeB, qp4);
}

// Fused per-layer kernel: attention (4 heads) + proj + gates + LN2 + FFN
// (+ next-layer LN1 + QKV). One row per block, 512 threads.
__global__ __launch_bounds__(512) void k_layer(
    const float* __restrict__ qb_, const float* __restrict__ kbT, const float* __restrict__ vbT,
    const float* __restrict__ qWeB, const float* __restrict__ qbeB,
    const float* __restrict__ edges,
    const float* __restrict__ We, const float* __restrict__ be,    // layer L (attn epilogue)
    const float* __restrict__ Wo, const float* __restrict__ bo,
    const float* __restrict__ Wg_a,
    const float* __restrict__ ln2s, const float* __restrict__ ln2b,
    const float* __restrict__ W1, const float* __restrict__ b1,
    const float* __restrict__ W2, const float* __restrict__ b2,
    const float* __restrict__ Wg_f,
    const float* __restrict__ xin, float* __restrict__ xout,
    int has_next,
    const float* __restrict__ ls_n, const float* __restrict__ lb_n,
    const float* __restrict__ Wq_n, const float* __restrict__ bq_n,
    const float* __restrict__ Wkv_n, const float* __restrict__ bkv_n,
    const float* __restrict__ We_n, const float* __restrict__ be_n,
    const float* __restrict__ cosS, const float* __restrict__ sinS,
    float* __restrict__ qb_o, float* __restrict__ kbT_o, float* __restrict__ vbT_o,
    float* __restrict__ qWeB_o, float* __restrict__ qbeB_o)
{
  __shared__ float qsL[256];
  __shared__ float qw[4][8];
  __shared__ float qbe[4];
  __shared__ __align__(16) float attnL[4][384];   // sim, then attn weights
  __shared__ float redA[8], redB[8];
  __shared__ float red8[8][8];
  __shared__ float part[512];
  __shared__ float ar[256];
  __shared__ float xold[128];
  __shared__ float xrow[128];
  __shared__ float snx[128];
  __shared__ float hs[512];
  __shared__ float4 prL[512];
  float* prF = (float*)prL;

  int i = swz_row(blockIdx.x);
  int t = threadIdx.x;

  // ---- stage q/qw/qbe/xold
  if (t < 256) qsL[t] = qb_[(size_t)i * 256 + t];
  else if (t < 288){ int idx = t - 256; qw[idx >> 3][idx & 7] = qWeB[((idx >> 3) * NTOK + i) * 8 + (idx & 7)]; }
  else if (t < 292) qbe[t - 288] = qbeB[(t - 288) * NTOK + i];
  else if (t >= 384) xold[t - 384] = xin[(size_t)i * 128 + (t - 384)];
  __syncthreads();

  // ---- sim: t<384 -> (h = t/96, j4 = t%96); 4 adjacent j per thread, float4 K^T reads
  if (t < 384){
    int h = t / 96, j4 = t % 96;
    const float4* kT4 = (const float4*)(kbT + (size_t)(h * 64) * NTOK) + j4;
    const float* qsp = qsL + h * 64;
    float sA = 0.f, sB = 0.f, sC = 0.f, sD = 0.f;
#pragma unroll 8
    for (int d = 0; d < 64; ++d){
      float4 kv = kT4[(size_t)d * (NTOK / 4)];
      float q = qsp[d];
      sA = fmaf(q, kv.x, sA); sB = fmaf(q, kv.y, sB);
      sC = fmaf(q, kv.z, sC); sD = fmaf(q, kv.w, sD);
    }
    int j0 = 4 * j4;
    const float4* ep4 = (const float4*)(edges + ((size_t)i * NTOK + j0) * 8);
    float qbv = qbe[h];
    float ed[4];
#pragma unroll
    for (int jj = 0; jj < 4; ++jj){
      float4 e0 = ep4[2 * jj], e1 = ep4[2 * jj + 1];
      ed[jj] = e0.x * qw[h][0] + e0.y * qw[h][1] + e0.z * qw[h][2] + e0.w * qw[h][3]
             + e1.x * qw[h][4] + e1.y * qw[h][5] + e1.z * qw[h][6] + e1.w * qw[h][7];
    }
    float4 sv;
    sv.x = 0.125f * (sA + ed[0] + qbv);
    sv.y = 0.125f * (sB + ed[1] + qbv);
    sv.z = 0.125f * (sC + ed[2] + qbv);
    sv.w = 0.125f * (sD + ed[3] + qbv);
    *(float4*)&attnL[h][j0] = sv;
  }
  __syncthreads();

  // ---- softmax per head: h = t>>7 (2 waves/head), jj = t&127, 3 j's per thread
  int h = t >> 7, jj = t & 127;
  int wv = t >> 6;
  float s0 = attnL[h][jj], s1 = attnL[h][jj + 128], s2 = attnL[h][jj + 256];
  float mx = wave_max64(fmaxf(s0, fmaxf(s1, s2)));
  if ((t & 63) == 0) redA[wv] = mx;
  __syncthreads();
  float gm = fmaxf(redA[2 * h], redA[2 * h + 1]);
  float ex0 = expf(s0 - gm), ex1 = expf(s1 - gm), ex2 = expf(s2 - gm);
  float sm = wave_sum64(ex0 + ex1 + ex2);
  if ((t & 63) == 0) redB[wv] = sm;
  __syncthreads();
  float inv = 1.0f / (redB[2 * h] + redB[2 * h + 1]);
  float w0 = ex0 * inv, w1 = ex1 * inv, w2 = ex2 * inv;
  attnL[h][jj] = w0; attnL[h][jj + 128] = w1; attnL[h][jj + 256] = w2;
  {
    // aw: re-read edges (hot in L1/L2)
    const float* ep = edges + ((size_t)i * NTOK + jj) * 8;
    float4 e00 = *(const float4*)ep;
    float4 e01 = *(const float4*)(ep + 4);
    ep += 128 * 8;
    float4 e10 = *(const float4*)ep;
    float4 e11 = *(const float4*)(ep + 4);
    ep += 128 * 8;
    float4 e20 = *(const float4*)ep;
    float4 e21 = *(const float4*)(ep + 4);
    float a8[8];
    a8[0] = w0 * e00.x + w1 * e10.x + w2 * e20.x;
    a8[1] = w0 * e00.y + w1 * e10.y + w2 * e20.y;
    a8[2] = w0 * e00.z + w1 * e10.z + w2 * e20.z;
    a8[3] = w0 * e00.w + w1 * e10.w + w2 * e20.w;
    a8[4] = w0 * e01.x + w1 * e11.x + w2 * e21.x;
    a8[5] = w0 * e01.y + w1 * e11.y + w2 * e21.y;
    a8[6] = w0 * e01.z + w1 * e11.z + w2 * e21.z;
    a8[7] = w0 * e01.w + w1 * e11.w + w2 * e21.w;
#pragma unroll
    for (int cc = 0; cc < 8; ++cc){
      float r = wave_sum64(a8[cc]);
      if ((t & 63) == 0) red8[wv][cc] = r;
    }
  }
  __syncthreads();   // attnL + red8 ready

  // ---- PV: t -> (h, d, half), contiguous float4 reads of vT[h][d][j]
  {
    int hh = t >> 7, dd = t & 63, half = (t >> 6) & 1;
    const float4* vT4 = (const float4*)(vbT + (size_t)(hh * 64 + dd) * NTOK) + half * 48;
    const float4* aw4 = (const float4*)(attnL[hh]) + half * 48;
    float a0 = 0.f, a1 = 0.f, a2 = 0.f, a3 = 0.f;
#pragma unroll 8
    for (int c = 0; c < 48; ++c){
      float4 v = vT4[c];
      float4 w = aw4[c];
      a0 = fmaf(w.x, v.x, a0); a1 = fmaf(w.y, v.y, a1);
      a2 = fmaf(w.z, v.z, a2); a3 = fmaf(w.w, v.w, a3);
    }
    part[t] = (a0 + a1) + (a2 + a3);
  }
  __syncthreads();
  if (t < 256){
    int h2 = t >> 6, d = t & 63;
    float o = part[h2 * 128 + d] + part[h2 * 128 + 64 + d];
    float ew = 0.f;
#pragma unroll
    for (int cc = 0; cc < 8; ++cc)
      ew = fmaf(red8[2 * h2][cc] + red8[2 * h2 + 1][cc], We[cc * 256 + h2 * 64 + d], ew);
    ar[t] = o + ew + be[h2 * 64 + d];
  }
  __syncthreads();

  // ---- proj: 128 outs, K=256. 32 colq x 16 ksub.
  {
    int colq = t & 31, ksub = t >> 5;
    const float4* Wo4 = (const float4*)Wo;
    float4 acc = {0.f, 0.f, 0.f, 0.f};
#pragma unroll
    for (int kk = 0; kk < 16; ++kk){
      int k = ksub * 16 + kk;
      float4 w = Wo4[(size_t)k * 32 + colq];
      float a = ar[k];
      acc.x = fmaf(a, w.x, acc.x); acc.y = fmaf(a, w.y, acc.y);
      acc.z = fmaf(a, w.z, acc.z); acc.w = fmaf(a, w.w, acc.w);
    }
    prL[ksub * 32 + colq] = acc;
  }
  __syncthreads();

  // ---- single-wave: proj-reduce + gate_a + LN2
  if (t < 64){
    float o0 = bo[t], o1 = bo[t + 64];
#pragma unroll
    for (int s = 0; s < 16; ++s){ o0 += prF[s * 128 + t]; o1 += prF[s * 128 + 64 + t]; }
    float xo0 = xold[t], xo1 = xold[t + 64];
    float gp = o0 * Wg_a[t]      + xo0 * Wg_a[128 + t] + (o0 - xo0) * Wg_a[256 + t]
             + o1 * Wg_a[64 + t] + xo1 * Wg_a[192 + t] + (o1 - xo1) * Wg_a[320 + t];
    float z = wave_sum64(gp);
    float gg = 1.0f / (1.0f + expf(-z));
    float xr0 = o0 * gg + xo0 * (1.0f - gg);
    float xr1 = o1 * gg + xo1 * (1.0f - gg);
    xrow[t] = xr0; xrow[t + 64] = xr1;
    float mu = wave_sum64(xr0 + xr1) * (1.0f / 128.0f);
    float d0 = xr0 - mu, d1 = xr1 - mu;
    float var = wave_sum64(d0 * d0 + d1 * d1) * (1.0f / 128.0f);
    float rstd = 1.0f / sqrtf(var + 1e-3f);
    snx[t]      = d0 * rstd * ln2s[t]      + ln2b[t];
    snx[t + 64] = d1 * rstd * ln2s[t + 64] + ln2b[t + 64];
  }
  __syncthreads();

  // ---- FFN1: 512 outs, K=128. 128 colq x 4 ksub.
  {
    int colq = t & 127, ksub = t >> 7;
    const float4* W14 = (const float4*)W1;
    float4 acc = {0.f, 0.f, 0.f, 0.f};
#pragma unroll 8
    for (int kk = 0; kk < 32; ++kk){
      int k = ksub * 32 + kk;
      float4 w = W14[(size_t)k * 128 + colq];
      float a = snx[k];
      acc.x = fmaf(a, w.x, acc.x); acc.y = fmaf(a, w.y, acc.y);
      acc.z = fmaf(a, w.z, acc.z); acc.w = fmaf(a, w.w, acc.w);
    }
    prL[ksub * 128 + colq] = acc;
  }
  __syncthreads();

  // ---- GELU reduce -> hs
  {
    float hv = b1[t];
#pragma unroll
    for (int s3 = 0; s3 < 4; ++s3) hv += prF[s3 * 512 + t];
    const float RS2 = 0.70710678118654752440f;
    hs[t] = 0.5f * hv * (1.0f + erff(hv * RS2));
  }
  __syncthreads();

  // ---- FFN2: 128 outs, K=512. 32 colq x 16 ksub.
  {
    int colq = t & 31, ksub = t >> 5;
    const float4* W24 = (const float4*)W2;
    float4 acc = {0.f, 0.f, 0.f, 0.f};
#pragma unroll 8
    for (int kk = 0; kk < 32; ++kk){
      int k = ksub * 32 + kk;
      float4 w = W24[(size_t)k * 32 + colq];
      float a = hs[k];
      acc.x = fmaf(a, w.x, acc.x); acc.y = fmaf(a, w.y, acc.y);
      acc.z = fmaf(a, w.z, acc.z); acc.w = fmaf(a, w.w, acc.w);
    }
    prL[ksub * 32 + colq] = acc;
  }
  __syncthreads();

  // ---- single-wave: FFN2-reduce + gate_f + xnew + next-layer LN1
  if (t < 64){
    float f0 = b2[t], f1 = b2[t + 64];
#pragma unroll
    for (int s3 = 0; s3 < 16; ++s3){ f0 += prF[s3 * 128 + t]; f1 += prF[s3 * 128 + 64 + t]; }
    float xr0 = xrow[t], xr1 = xrow[t + 64];
    float gp = f0 * Wg_f[t]      + xr0 * Wg_f[128 + t] + (f0 - xr0) * Wg_f[256 + t]
             + f1 * Wg_f[64 + t] + xr1 * Wg_f[192 + t] + (f1 - xr1) * Wg_f[320 + t];
    float z = wave_sum64(gp);
    float gg = 1.0f / (1.0f + expf(-z));
    float xn0 = f0 * gg + xr0 * (1.0f - gg);
    float xn1 = f1 * gg + xr1 * (1.0f - gg);
    xout[(size_t)i * 128 + t]      = xn0;
    xout[(size_t)i * 128 + 64 + t] = xn1;
    if (has_next){
      float mu = wave_sum64(xn0 + xn1) * (1.0f / 128.0f);
      float d0 = xn0 - mu, d1 = xn1 - mu;
      float var = wave_sum64(d0 * d0 + d1 * d1) * (1.0f / 128.0f);
      float rstd = 1.0f / sqrtf(var + 1e-3f);
      snx[t]      = d0 * rstd * ls_n[t]      + lb_n[t];
      snx[t + 64] = d1 * rstd * ls_n[t + 64] + lb_n[t + 64];
    }
  }
  __syncthreads();

  if (has_next){
    qkv_row_v2(i, t, snx, Wq_n, bq_n, Wkv_n, bkv_n, We_n, be_n,
               cosS + (size_t)i * 64, sinS + (size_t)i * 64,
               qb_o, kbT_o, vbT_o, qWeB_o, qbeB_o, prL);
  }
}

// Final head. Single block, 384 threads.
__global__ __launch_bounds__(384) void k_final(
    const float* __restrict__ x,
    const float* __restrict__ Wd1, const float* __restrict__ bd1,
    const float* __restrict__ Wd2, const float* __restrict__ bd2,
    float* __restrict__ out)
{
  __shared__ float red[6];
  int i = threadIdx.x;
  float y[9];
#pragma unroll
  for (int c = 0; c < 9; ++c) y[c] = bd1[c];
  const float4* x4 = (const float4*)(x + (size_t)i * 128);
#pragma unroll 8
  for (int r4 = 0; r4 < 32; ++r4){
    float4 xv = x4[r4];
    const float* wp = Wd1 + (r4 * 4) * 9;
#pragma unroll
    for (int c = 0; c < 9; ++c) y[c] = fmaf(xv.x, wp[c], y[c]);
#pragma unroll
    for (int c = 0; c < 9; ++c) y[c] = fmaf(xv.y, wp[9 + c], y[c]);
#pragma unroll
    for (int c = 0; c < 9; ++c) y[c] = fmaf(xv.z, wp[18 + c], y[c]);
#pragma unroll
    for (int c = 0; c < 9; ++c) y[c] = fmaf(xv.w, wp[27 + c], y[c]);
  }
#pragma unroll
  for (int c = 0; c < 9; ++c) y[c] = fmaxf(y[c], 0.0f);
  float z[3];
#pragma unroll
  for (int c = 0; c < 3; ++c){
    float a = bd2[c];
#pragma unroll
    for (int r = 0; r < 9; ++r) a = fmaf(y[r], Wd2[r * 3 + c], a);
    z[c] = a;
  }
#pragma unroll
  for (int c = 0; c < 3; ++c){
    float s = wave_sum64(z[c]);
    if ((i & 63) == 0) red[i >> 6] = s;
    __syncthreads();
    float tot = 0.f;
#pragma unroll
    for (int w = 0; w < 6; ++w) tot += red[w];
    float mean = tot * (1.0f / 384.0f);
    out[i * 3 + c] = z[c] - mean;
    __syncthreads();
  }
}

extern "C" void kernel_launch(void* const* d_in, const int* in_sizes, int n_in,
                              void* d_out, int out_size, void* d_ws, size_t ws_size,
                              hipStream_t stream)
{
  const float* nodes   = (const float*)d_in[0];
  const float* edges   = (const float*)d_in[1];
  const float* ln1_s   = (const float*)d_in[2];
  const float* ln1_b   = (const float*)d_in[3];
  const float* Wq      = (const float*)d_in[4];
  const float* bq      = (const float*)d_in[5];
  const float* Wkv     = (const float*)d_in[6];
  const float* bkv     = (const float*)d_in[7];
  const float* We      = (const float*)d_in[8];
  const float* be      = (const float*)d_in[9];
  const float* Wo      = (const float*)d_in[10];
  const float* bo      = (const float*)d_in[11];
  const float* Wg_attn = (const float*)d_in[12];
  const float* ln2_s   = (const float*)d_in[13];
  const float* ln2_b   = (const float*)d_in[14];
  const float* W1      = (const float*)d_in[15];
  const float* b1      = (const float*)d_in[16];
  const float* W2      = (const float*)d_in[17];
  const float* b2      = (const float*)d_in[18];
  const float* Wg_ff   = (const float*)d_in[19];
  const float* Wd1     = (const float*)d_in[20];
  const float* bd1     = (const float*)d_in[21];
  const float* Wd2     = (const float*)d_in[22];
  const float* bd2     = (const float*)d_in[23];
  // d_in[24] = mask: all-true; no-op in the math.

  float* ws   = (float*)d_ws;
  float* cosS = ws;                  // 384*64
  float* sinS = cosS + 24576;
  // double-buffered q/k/v sets (layer parity)
  float* qb0   = sinS + 24576;       // 384*256
  float* kbT0  = qb0 + 98304;        // [4][64][384]
  float* vbT0  = kbT0 + 98304;       // [4][64][384] transposed V
  float* qWe0  = vbT0 + 98304;       // 4*384*8
  float* qbe0  = qWe0 + 12288;       // 4*384
  float* qb1   = qbe0 + 1536;
  float* kbT1  = qb1 + 98304;
  float* vbT1  = kbT1 + 98304;
  float* qWe1  = vbT1 + 98304;
  float* qbe1  = qWe1 + 12288;
  float* xbuf  = qbe1 + 1536;        // 384*128

  k_lnqkv<<<dim3(NTOK), dim3(512), 0, stream>>>(
      nodes, ln1_s, ln1_b, Wq, bq, Wkv, bkv, We, be,
      cosS, sinS, qb0, kbT0, vbT0, qWe0, qbe0);

  for (int L = 0; L < DEPTH; ++L){
    int Ln = (L < DEPTH - 1) ? (L + 1) : L;
    const float* qbi  = (L & 1) ? qb1  : qb0;
    const float* kbi  = (L & 1) ? kbT1 : kbT0;
    const float* vbi  = (L & 1) ? vbT1 : vbT0;
    const float* qWei = (L & 1) ? qWe1 : qWe0;
    const float* qbei = (L & 1) ? qbe1 : qbe0;
    float* qbo  = (L & 1) ? qb0  : qb1;
    float* kbo  = (L & 1) ? kbT0 : kbT1;
    float* vbo  = (L & 1) ? vbT0 : vbT1;
    float* qWeo = (L & 1) ? qWe0 : qWe1;
    float* qbeo = (L & 1) ? qbe0 : qbe1;

    k_layer<<<dim3(NTOK), dim3(512), 0, stream>>>(
        qbi, kbi, vbi, qWei, qbei, edges,
        We + (size_t)L * EDGE * INNER, be + L * INNER,
        Wo + (size_t)L * INNER * DIM, bo + L * DIM,
        Wg_attn + L * 3 * DIM,
        ln2_s + L * DIM, ln2_b + L * DIM,
        W1 + (size_t)L * DIM * FFD, b1 + L * FFD,
        W2 + (size_t)L * FFD * DIM, b2 + L * DIM,
        Wg_ff + L * 3 * DIM,
        (L == 0) ? nodes : xbuf, xbuf,
        (L < DEPTH - 1) ? 1 : 0,
        ln1_s + Ln * DIM, ln1_b + Ln * DIM,
        Wq + (size_t)Ln * DIM * INNER, bq + Ln * INNER,
        Wkv + (size_t)Ln * DIM * 2 * INNER, bkv + Ln * 2 * INNER,
        We + (size_t)Ln * EDGE * INNER, be + Ln * INNER,
        cosS, sinS, qbo, kbo, vbo, qWeo, qbeo);
  }

  k_final<<<dim3(1), dim3(384), 0, stream>>>(xbuf, Wd1, bd1, Wd2, bd2, (float*)d_out);
}

// Round 12
// 138.084 us; speedup vs baseline: 1.3008x; 1.3008x over previous
//
#include <hip/hip_runtime.h>
#include <math.h>

#define NTOK 384
#define DIM  128
#define HEADS 4
#define DHEAD 64
#define INNER 256
#define DEPTH 3
#define EDGE 8
#define FFD 512

__device__ __forceinline__ float wave_sum64(float v){
#pragma unroll
  for (int m = 32; m >= 1; m >>= 1) v += __shfl_xor(v, m, 64);
  return v;
}
__device__ __forceinline__ float wave_max64(float v){
#pragma unroll
  for (int m = 32; m >= 1; m >>= 1) v = fmaxf(v, __shfl_xor(v, m, 64));
  return v;
}
// 32-lane segment reductions (for 96-thread-per-head mappings).
__device__ __forceinline__ float seg_sum32(float v){
#pragma unroll
  for (int m = 16; m >= 1; m >>= 1) v += __shfl_xor(v, m, 32);
  return v;
}
__device__ __forceinline__ float seg_max32(float v){
#pragma unroll
  for (int m = 16; m >= 1; m >>= 1) v = fmaxf(v, __shfl_xor(v, m, 32));
  return v;
}

// XCD-pinned row mapping: 384 = 8 XCDs x 48 rows.
__device__ __forceinline__ int swz_row(int id){ return (id & 7) * 48 + (id >> 3); }

// Rotary for one (i, d): numpy float32 semantics via double precision then round.
__device__ __forceinline__ void rotary_val(int i, int d, float* c, float* s){
  int j = d >> 1;
  double ex = (double)(2 * j) / 64.0;
  float p = (float)pow(10000.0, ex);
  float inv = 1.0f / p;
  float f = (float)i * inv;
  double fd = (double)f;
  *c = (float)cos(fd);
  *s = (float)sin(fd);
}

// QKV (+rotary, qWe, qbe) for ONE row. Block >= 512 threads.
// t<192 -> (quad=t, ks=0); 192<=t<384 -> (quad=t-192, ks=1).
// quad 0-63: q col-quad; 64-127: k (transposed store); 128-191: v (row-major).
// Contains 1 barrier (all threads reach it).
__device__ __forceinline__ void qkv_row_v2(
    int i, int t, const float* __restrict__ snx,
    const float* __restrict__ Wq, const float* __restrict__ bq,
    const float* __restrict__ Wkv, const float* __restrict__ bkv,
    const float* __restrict__ We, const float* __restrict__ be,
    const float* __restrict__ cosRow, const float* __restrict__ sinRow,
    float* __restrict__ qb_, float* __restrict__ kbT, float* __restrict__ vb_,
    float* __restrict__ qWeB, float* __restrict__ qbeB,
    float4* __restrict__ qp4)     // LDS, 192 float4
{
  int ks   = (t < 192) ? 0 : 1;
  int quad = (t < 192) ? t : t - 192;
  float4 acc = {0.f, 0.f, 0.f, 0.f};
  if (t < 384){
    const float4* Wp; int stride4;
    if (quad < 64){ Wp = (const float4*)Wq + quad;         stride4 = 64;  }
    else          { Wp = (const float4*)Wkv + (quad - 64); stride4 = 128; }
    int k0 = ks * 64;
#pragma unroll 8
    for (int kk = 0; kk < 64; ++kk){
      int k = k0 + kk;
      float4 w = Wp[(size_t)k * stride4];
      float x = snx[k];
      acc.x = fmaf(x, w.x, acc.x); acc.y = fmaf(x, w.y, acc.y);
      acc.z = fmaf(x, w.z, acc.z); acc.w = fmaf(x, w.w, acc.w);
    }
    if (ks == 1) qp4[quad] = acc;
  }
  __syncthreads();
  if (t < 192){
    float4 p = qp4[quad];
    acc.x += p.x; acc.y += p.y; acc.z += p.z; acc.w += p.w;
    if (quad < 64){
      int c0 = 4 * quad;
      float4 b = ((const float4*)bq)[quad];
      float a0 = acc.x + b.x, a1 = acc.y + b.y, a2 = acc.z + b.z, a3 = acc.w + b.w;
      int d0 = c0 & 63;
      float c_0 = cosRow[d0],     s_0 = sinRow[d0];
      float c_1 = cosRow[d0 + 2], s_1 = sinRow[d0 + 2];
      float r0 = a0 * c_0 - a1 * s_0;
      float r1 = a1 * c_0 + a0 * s_0;
      float r2 = a2 * c_1 - a3 * s_1;
      float r3 = a3 * c_1 + a2 * s_1;
      float4 qv; qv.x = r0; qv.y = r1; qv.z = r2; qv.w = r3;
      *(float4*)(qb_ + (size_t)i * 256 + c0) = qv;
      int h = quad >> 4;
#pragma unroll
      for (int cc = 0; cc < 8; ++cc){
        const float* wc = We + cc * 256 + c0;
        float pr = r0 * wc[0] + r1 * wc[1] + r2 * wc[2] + r3 * wc[3];
#pragma unroll
        for (int m = 8; m >= 1; m >>= 1) pr += __shfl_xor(pr, m, 16);
        if ((t & 15) == 0) qWeB[(h * NTOK + i) * 8 + cc] = pr;
      }
      const float* bc = be + c0;
      float pb = r0 * bc[0] + r1 * bc[1] + r2 * bc[2] + r3 * bc[3];
#pragma unroll
      for (int m = 8; m >= 1; m >>= 1) pb += __shfl_xor(pb, m, 16);
      if ((t & 15) == 0) qbeB[h * NTOK + i] = pb;
    } else if (quad < 128){
      int c0 = 4 * (quad - 64);
      float4 b = ((const float4*)bkv)[quad - 64];
      float a0 = acc.x + b.x, a1 = acc.y + b.y, a2 = acc.z + b.z, a3 = acc.w + b.w;
      int d0 = c0 & 63, h = c0 >> 6;
      float c_0 = cosRow[d0],     s_0 = sinRow[d0];
      float c_1 = cosRow[d0 + 2], s_1 = sinRow[d0 + 2];
      float r0 = a0 * c_0 - a1 * s_0;
      float r1 = a1 * c_0 + a0 * s_0;
      float r2 = a2 * c_1 - a3 * s_1;
      float r3 = a3 * c_1 + a2 * s_1;
      float* kp = kbT + (size_t)(h * 64 + d0) * NTOK + i;
      kp[0]        = r0;
      kp[NTOK]     = r1;
      kp[2 * NTOK] = r2;
      kp[3 * NTOK] = r3;
    } else {
      int vq = quad - 128;
      int c0 = 4 * vq;
      float4 b = ((const float4*)bkv)[64 + vq];
      float4 vv;
      vv.x = acc.x + b.x; vv.y = acc.y + b.y;
      vv.z = acc.z + b.z; vv.w = acc.w + b.w;
      *(float4*)(vb_ + (size_t)i * 256 + c0) = vv;
    }
  }
}

// Layer-0: rotary + LN1 (single wave) + QKV. 512 thr/row.
__global__ __launch_bounds__(512) void k_lnqkv(
    const float* __restrict__ x,
    const float* __restrict__ ls, const float* __restrict__ lb,
    const float* __restrict__ Wq, const float* __restrict__ bq,
    const float* __restrict__ Wkv, const float* __restrict__ bkv,
    const float* __restrict__ We, const float* __restrict__ be,
    float* __restrict__ cosS, float* __restrict__ sinS,
    float* __restrict__ qb_, float* __restrict__ kbT, float* __restrict__ vb_,
    float* __restrict__ qWeB, float* __restrict__ qbeB)
{
  __shared__ float snx[128];
  __shared__ float crow[64], srow[64];
  __shared__ float4 qp4[192];
  int i = swz_row(blockIdx.x);
  int t = threadIdx.x;

  if (t >= 448){
    int d = t - 448;
    float c, s;
    rotary_val(i, d, &c, &s);
    crow[d] = c; srow[d] = s;
    cosS[i * 64 + d] = c; sinS[i * 64 + d] = s;
  }
  if (t < 64){
    float x0 = x[(size_t)i * 128 + t], x1 = x[(size_t)i * 128 + 64 + t];
    float mu = wave_sum64(x0 + x1) * (1.0f / 128.0f);
    float d0 = x0 - mu, d1 = x1 - mu;
    float var = wave_sum64(d0 * d0 + d1 * d1) * (1.0f / 128.0f);
    float rstd = 1.0f / sqrtf(var + 1e-3f);
    snx[t]      = d0 * rstd * ls[t]      + lb[t];
    snx[t + 64] = d1 * rstd * ls[t + 64] + lb[t + 64];
  }
  __syncthreads();
  qkv_row_v2(i, t, snx, Wq, bq, Wkv, bkv, We, be, crow, srow,
             qb_, kbT, vb_, qWeB, qbeB, qp4);
}

// Fused per-layer kernel: attention (4 heads) + proj + gates + LN2 + FFN
// (+ next-layer LN1 + QKV). One row per block, 512 threads.
__global__ __launch_bounds__(512) void k_layer(
    const float* __restrict__ qb_, const float* __restrict__ kbT, const float* __restrict__ vb_,
    const float* __restrict__ qWeB, const float* __restrict__ qbeB,
    const float* __restrict__ edges,
    const float* __restrict__ We, const float* __restrict__ be,    // layer L (attn epilogue)
    const float* __restrict__ Wo, const float* __restrict__ bo,
    const float* __restrict__ Wg_a,
    const float* __restrict__ ln2s, const float* __restrict__ ln2b,
    const float* __restrict__ W1, const float* __restrict__ b1,
    const float* __restrict__ W2, const float* __restrict__ b2,
    const float* __restrict__ Wg_f,
    const float* __restrict__ xin, float* __restrict__ xout,
    int has_next,
    const float* __restrict__ ls_n, const float* __restrict__ lb_n,
    const float* __restrict__ Wq_n, const float* __restrict__ bq_n,
    const float* __restrict__ Wkv_n, const float* __restrict__ bkv_n,
    const float* __restrict__ We_n, const float* __restrict__ be_n,
    const float* __restrict__ cosS, const float* __restrict__ sinS,
    float* __restrict__ qb_o, float* __restrict__ kbT_o, float* __restrict__ vb_o,
    float* __restrict__ qWeB_o, float* __restrict__ qbeB_o)
{
  __shared__ float qsL[256];
  __shared__ float qw[4][8];
  __shared__ float qbe[4];
  __shared__ __align__(16) float attnL[4][384];   // attn weights
  __shared__ float redA[12], redB[12];
  __shared__ float red8[12][8];
  __shared__ float part[512];
  __shared__ float ar[256];
  __shared__ float xold[128];
  __shared__ float xrow[128];
  __shared__ float snx[128];
  __shared__ float hs[512];
  __shared__ float4 prL[512];
  float* prF = (float*)prL;

  int i = swz_row(blockIdx.x);
  int t = threadIdx.x;

  // ---- stage q/qw/qbe/xold
  if (t < 256) qsL[t] = qb_[(size_t)i * 256 + t];
  else if (t < 288){ int idx = t - 256; qw[idx >> 3][idx & 7] = qWeB[((idx >> 3) * NTOK + i) * 8 + (idx & 7)]; }
  else if (t < 292) qbe[t - 288] = qbeB[(t - 288) * NTOK + i];
  else if (t >= 384) xold[t - 384] = xin[(size_t)i * 128 + (t - 384)];
  __syncthreads();

  // ---- sim + softmax + aw in quad ownership: t<384 -> (h = t/96, j4 = t%96)
  // Each thread owns 4 adjacent j. float4 K^T reads (lanes = adjacent quads ->
  // 1KB/wave coalesced). Per-head reductions = 3x 32-lane segments.
  if (t < 384){
    int h = t / 96, j4 = t % 96;
    int j0 = 4 * j4;
    const float4* kT4 = (const float4*)(kbT + (size_t)(h * 64) * NTOK) + j4;
    const float* qsp = qsL + h * 64;
    float sA = 0.f, sB = 0.f, sC = 0.f, sD = 0.f;
#pragma unroll 8
    for (int d = 0; d < 64; ++d){
      float4 kv = kT4[(size_t)d * (NTOK / 4)];
      float q = qsp[d];
      sA = fmaf(q, kv.x, sA); sB = fmaf(q, kv.y, sB);
      sC = fmaf(q, kv.z, sC); sD = fmaf(q, kv.w, sD);
    }
    const float4* ep4 = (const float4*)(edges + ((size_t)i * NTOK + j0) * 8);
    float4 e0s[4], e1s[4];
    float ed[4];
#pragma unroll
    for (int jj = 0; jj < 4; ++jj){
      float4 e0 = ep4[2 * jj], e1 = ep4[2 * jj + 1];
      e0s[jj] = e0; e1s[jj] = e1;
      ed[jj] = e0.x * qw[h][0] + e0.y * qw[h][1] + e0.z * qw[h][2] + e0.w * qw[h][3]
             + e1.x * qw[h][4] + e1.y * qw[h][5] + e1.z * qw[h][6] + e1.w * qw[h][7];
    }
    float qbv = qbe[h];
    float s0 = 0.125f * (sA + ed[0] + qbv);
    float s1 = 0.125f * (sB + ed[1] + qbv);
    float s2 = 0.125f * (sC + ed[2] + qbv);
    float s3 = 0.125f * (sD + ed[3] + qbv);

    // segmented max (seg = t>>5; head h = segs 3h..3h+2)
    float mx = seg_max32(fmaxf(fmaxf(s0, s1), fmaxf(s2, s3)));
    if ((t & 31) == 0) redA[t >> 5] = mx;
    __syncthreads();
    float gm = fmaxf(fmaxf(redA[3 * h], redA[3 * h + 1]), redA[3 * h + 2]);
    float ex0 = expf(s0 - gm), ex1 = expf(s1 - gm), ex2 = expf(s2 - gm), ex3 = expf(s3 - gm);
    float sm = seg_sum32((ex0 + ex1) + (ex2 + ex3));
    if ((t & 31) == 0) redB[t >> 5] = sm;
    __syncthreads();
    float inv = 1.0f / (redB[3 * h] + redB[3 * h + 1] + redB[3 * h + 2]);
    float w0 = ex0 * inv, w1 = ex1 * inv, w2 = ex2 * inv, w3 = ex3 * inv;
    float4 wvv; wvv.x = w0; wvv.y = w1; wvv.z = w2; wvv.w = w3;
    *(float4*)&attnL[h][j0] = wvv;

    // aw from registers
    float a8[8];
    a8[0] = w0 * e0s[0].x + w1 * e0s[1].x + w2 * e0s[2].x + w3 * e0s[3].x;
    a8[1] = w0 * e0s[0].y + w1 * e0s[1].y + w2 * e0s[2].y + w3 * e0s[3].y;
    a8[2] = w0 * e0s[0].z + w1 * e0s[1].z + w2 * e0s[2].z + w3 * e0s[3].z;
    a8[3] = w0 * e0s[0].w + w1 * e0s[1].w + w2 * e0s[2].w + w3 * e0s[3].w;
    a8[4] = w0 * e1s[0].x + w1 * e1s[1].x + w2 * e1s[2].x + w3 * e1s[3].x;
    a8[5] = w0 * e1s[0].y + w1 * e1s[1].y + w2 * e1s[2].y + w3 * e1s[3].y;
    a8[6] = w0 * e1s[0].z + w1 * e1s[1].z + w2 * e1s[2].z + w3 * e1s[3].z;
    a8[7] = w0 * e1s[0].w + w1 * e1s[1].w + w2 * e1s[2].w + w3 * e1s[3].w;
#pragma unroll
    for (int cc = 0; cc < 8; ++cc){
      float r = seg_sum32(a8[cc]);
      if ((t & 31) == 0) red8[t >> 5][cc] = r;
    }
  } else {
    __syncthreads();
    __syncthreads();
  }
  __syncthreads();   // attnL + red8 ready

  // ---- PV: t -> (h, d, half); lanes = adjacent d -> coalesced 256B lines
  {
    int hh = t >> 7, dd = t & 63, half = (t >> 6) & 1;
    const float* vp = vb_ + hh * 64 + dd;
    const float* aw_ = attnL[hh];
    int j0 = half * 192;
    float va = 0.f, vb2 = 0.f;
#pragma unroll 8
    for (int jj2 = 0; jj2 < 192; jj2 += 2){
      va  = fmaf(aw_[j0 + jj2],     vp[(size_t)(j0 + jj2) * 256],     va);
      vb2 = fmaf(aw_[j0 + jj2 + 1], vp[(size_t)(j0 + jj2 + 1) * 256], vb2);
    }
    part[t] = va + vb2;
  }
  __syncthreads();
  if (t < 256){
    int h2 = t >> 6, d = t & 63;
    float o = part[h2 * 128 + d] + part[h2 * 128 + 64 + d];
    float ew = 0.f;
#pragma unroll
    for (int cc = 0; cc < 8; ++cc)
      ew = fmaf(red8[3 * h2][cc] + red8[3 * h2 + 1][cc] + red8[3 * h2 + 2][cc],
                We[cc * 256 + h2 * 64 + d], ew);
    ar[t] = o + ew + be[h2 * 64 + d];
  }
  __syncthreads();

  // ---- proj: 128 outs, K=256. 32 colq x 16 ksub.
  {
    int colq = t & 31, ksub = t >> 5;
    const float4* Wo4 = (const float4*)Wo;
    float4 acc = {0.f, 0.f, 0.f, 0.f};
#pragma unroll
    for (int kk = 0; kk < 16; ++kk){
      int k = ksub * 16 + kk;
      float4 w = Wo4[(size_t)k * 32 + colq];
      float a = ar[k];
      acc.x = fmaf(a, w.x, acc.x); acc.y = fmaf(a, w.y, acc.y);
      acc.z = fmaf(a, w.z, acc.z); acc.w = fmaf(a, w.w, acc.w);
    }
    prL[ksub * 32 + colq] = acc;
  }
  __syncthreads();

  // ---- single-wave: proj-reduce + gate_a + LN2
  if (t < 64){
    float o0 = bo[t], o1 = bo[t + 64];
#pragma unroll
    for (int s = 0; s < 16; ++s){ o0 += prF[s * 128 + t]; o1 += prF[s * 128 + 64 + t]; }
    float xo0 = xold[t], xo1 = xold[t + 64];
    float gp = o0 * Wg_a[t]      + xo0 * Wg_a[128 + t] + (o0 - xo0) * Wg_a[256 + t]
             + o1 * Wg_a[64 + t] + xo1 * Wg_a[192 + t] + (o1 - xo1) * Wg_a[320 + t];
    float z = wave_sum64(gp);
    float gg = 1.0f / (1.0f + expf(-z));
    float xr0 = o0 * gg + xo0 * (1.0f - gg);
    float xr1 = o1 * gg + xo1 * (1.0f - gg);
    xrow[t] = xr0; xrow[t + 64] = xr1;
    float mu = wave_sum64(xr0 + xr1) * (1.0f / 128.0f);
    float d0 = xr0 - mu, d1 = xr1 - mu;
    float var = wave_sum64(d0 * d0 + d1 * d1) * (1.0f / 128.0f);
    float rstd = 1.0f / sqrtf(var + 1e-3f);
    snx[t]      = d0 * rstd * ln2s[t]      + ln2b[t];
    snx[t + 64] = d1 * rstd * ln2s[t + 64] + ln2b[t + 64];
  }
  __syncthreads();

  // ---- FFN1: 512 outs, K=128. 128 colq x 4 ksub.
  {
    int colq = t & 127, ksub = t >> 7;
    const float4* W14 = (const float4*)W1;
    float4 acc = {0.f, 0.f, 0.f, 0.f};
#pragma unroll 8
    for (int kk = 0; kk < 32; ++kk){
      int k = ksub * 32 + kk;
      float4 w = W14[(size_t)k * 128 + colq];
      float a = snx[k];
      acc.x = fmaf(a, w.x, acc.x); acc.y = fmaf(a, w.y, acc.y);
      acc.z = fmaf(a, w.z, acc.z); acc.w = fmaf(a, w.w, acc.w);
    }
    prL[ksub * 128 + colq] = acc;
  }
  __syncthreads();

  // ---- GELU reduce -> hs
  {
    float hv = b1[t];
#pragma unroll
    for (int s3 = 0; s3 < 4; ++s3) hv += prF[s3 * 512 + t];
    const float RS2 = 0.70710678118654752440f;
    hs[t] = 0.5f * hv * (1.0f + erff(hv * RS2));
  }
  __syncthreads();

  // ---- FFN2: 128 outs, K=512. 32 colq x 16 ksub.
  {
    int colq = t & 31, ksub = t >> 5;
    const float4* W24 = (const float4*)W2;
    float4 acc = {0.f, 0.f, 0.f, 0.f};
#pragma unroll 8
    for (int kk = 0; kk < 32; ++kk){
      int k = ksub * 32 + kk;
      float4 w = W24[(size_t)k * 32 + colq];
      float a = hs[k];
      acc.x = fmaf(a, w.x, acc.x); acc.y = fmaf(a, w.y, acc.y);
      acc.z = fmaf(a, w.z, acc.z); acc.w = fmaf(a, w.w, acc.w);
    }
    prL[ksub * 32 + colq] = acc;
  }
  __syncthreads();

  // ---- single-wave: FFN2-reduce + gate_f + xnew + next-layer LN1
  if (t < 64){
    float f0 = b2[t], f1 = b2[t + 64];
#pragma unroll
    for (int s3 = 0; s3 < 16; ++s3){ f0 += prF[s3 * 128 + t]; f1 += prF[s3 * 128 + 64 + t]; }
    float xr0 = xrow[t], xr1 = xrow[t + 64];
    float gp = f0 * Wg_f[t]      + xr0 * Wg_f[128 + t] + (f0 - xr0) * Wg_f[256 + t]
             + f1 * Wg_f[64 + t] + xr1 * Wg_f[192 + t] + (f1 - xr1) * Wg_f[320 + t];
    float z = wave_sum64(gp);
    float gg = 1.0f / (1.0f + expf(-z));
    float xn0 = f0 * gg + xr0 * (1.0f - gg);
    float xn1 = f1 * gg + xr1 * (1.0f - gg);
    xout[(size_t)i * 128 + t]      = xn0;
    xout[(size_t)i * 128 + 64 + t] = xn1;
    if (has_next){
      float mu = wave_sum64(xn0 + xn1) * (1.0f / 128.0f);
      float d0 = xn0 - mu, d1 = xn1 - mu;
      float var = wave_sum64(d0 * d0 + d1 * d1) * (1.0f / 128.0f);
      float rstd = 1.0f / sqrtf(var + 1e-3f);
      snx[t]      = d0 * rstd * ls_n[t]      + lb_n[t];
      snx[t + 64] = d1 * rstd * ls_n[t + 64] + lb_n[t + 64];
    }
  }
  __syncthreads();

  if (has_next){
    qkv_row_v2(i, t, snx, Wq_n, bq_n, Wkv_n, bkv_n, We_n, be_n,
               cosS + (size_t)i * 64, sinS + (size_t)i * 64,
               qb_o, kbT_o, vb_o, qWeB_o, qbeB_o, prL);
  }
}

// Final head. Single block, 384 threads.
__global__ __launch_bounds__(384) void k_final(
    const float* __restrict__ x,
    const float* __restrict__ Wd1, const float* __restrict__ bd1,
    const float* __restrict__ Wd2, const float* __restrict__ bd2,
    float* __restrict__ out)
{
  __shared__ float red[6];
  int i = threadIdx.x;
  float y[9];
#pragma unroll
  for (int c = 0; c < 9; ++c) y[c] = bd1[c];
  const float4* x4 = (const float4*)(x + (size_t)i * 128);
#pragma unroll 8
  for (int r4 = 0; r4 < 32; ++r4){
    float4 xv = x4[r4];
    const float* wp = Wd1 + (r4 * 4) * 9;
#pragma unroll
    for (int c = 0; c < 9; ++c) y[c] = fmaf(xv.x, wp[c], y[c]);
#pragma unroll
    for (int c = 0; c < 9; ++c) y[c] = fmaf(xv.y, wp[9 + c], y[c]);
#pragma unroll
    for (int c = 0; c < 9; ++c) y[c] = fmaf(xv.z, wp[18 + c], y[c]);
#pragma unroll
    for (int c = 0; c < 9; ++c) y[c] = fmaf(xv.w, wp[27 + c], y[c]);
  }
#pragma unroll
  for (int c = 0; c < 9; ++c) y[c] = fmaxf(y[c], 0.0f);
  float z[3];
#pragma unroll
  for (int c = 0; c < 3; ++c){
    float a = bd2[c];
#pragma unroll
    for (int r = 0; r < 9; ++r) a = fmaf(y[r], Wd2[r * 3 + c], a);
    z[c] = a;
  }
#pragma unroll
  for (int c = 0; c < 3; ++c){
    float s = wave_sum64(z[c]);
    if ((i & 63) == 0) red[i >> 6] = s;
    __syncthreads();
    float tot = 0.f;
#pragma unroll
    for (int w = 0; w < 6; ++w) tot += red[w];
    float mean = tot * (1.0f / 384.0f);
    out[i * 3 + c] = z[c] - mean;
    __syncthreads();
  }
}

extern "C" void kernel_launch(void* const* d_in, const int* in_sizes, int n_in,
                              void* d_out, int out_size, void* d_ws, size_t ws_size,
                              hipStream_t stream)
{
  const float* nodes   = (const float*)d_in[0];
  const float* edges   = (const float*)d_in[1];
  const float* ln1_s   = (const float*)d_in[2];
  const float* ln1_b   = (const float*)d_in[3];
  const float* Wq      = (const float*)d_in[4];
  const float* bq      = (const float*)d_in[5];
  const float* Wkv     = (const float*)d_in[6];
  const float* bkv     = (const float*)d_in[7];
  const float* We      = (const float*)d_in[8];
  const float* be      = (const float*)d_in[9];
  const float* Wo      = (const float*)d_in[10];
  const float* bo      = (const float*)d_in[11];
  const float* Wg_attn = (const float*)d_in[12];
  const float* ln2_s   = (const float*)d_in[13];
  const float* ln2_b   = (const float*)d_in[14];
  const float* W1      = (const float*)d_in[15];
  const float* b1      = (const float*)d_in[16];
  const float* W2      = (const float*)d_in[17];
  const float* b2      = (const float*)d_in[18];
  const float* Wg_ff   = (const float*)d_in[19];
  const float* Wd1     = (const float*)d_in[20];
  const float* bd1     = (const float*)d_in[21];
  const float* Wd2     = (const float*)d_in[22];
  const float* bd2     = (const float*)d_in[23];
  // d_in[24] = mask: all-true; no-op in the math.

  float* ws   = (float*)d_ws;
  float* cosS = ws;                  // 384*64
  float* sinS = cosS + 24576;
  // double-buffered q/k/v sets (layer parity)
  float* qb0   = sinS + 24576;       // 384*256
  float* kbT0  = qb0 + 98304;        // [4][64][384]
  float* vb0   = kbT0 + 98304;       // row-major V
  float* qWe0  = vb0 + 98304;        // 4*384*8
  float* qbe0  = qWe0 + 12288;       // 4*384
  float* qb1   = qbe0 + 1536;
  float* kbT1  = qb1 + 98304;
  float* vb1   = kbT1 + 98304;
  float* qWe1  = vb1 + 98304;
  float* qbe1  = qWe1 + 12288;
  float* xbuf  = qbe1 + 1536;        // 384*128

  k_lnqkv<<<dim3(NTOK), dim3(512), 0, stream>>>(
      nodes, ln1_s, ln1_b, Wq, bq, Wkv, bkv, We, be,
      cosS, sinS, qb0, kbT0, vb0, qWe0, qbe0);

  for (int L = 0; L < DEPTH; ++L){
    int Ln = (L < DEPTH - 1) ? (L + 1) : L;
    const float* qbi  = (L & 1) ? qb1  : qb0;
    const float* kbi  = (L & 1) ? kbT1 : kbT0;
    const float* vbi  = (L & 1) ? vb1  : vb0;
    const float* qWei = (L & 1) ? qWe1 : qWe0;
    const float* qbei = (L & 1) ? qbe1 : qbe0;
    float* qbo  = (L & 1) ? qb0  : qb1;
    float* kbo  = (L & 1) ? kbT0 : kbT1;
    float* vbo  = (L & 1) ? vb0  : vb1;
    float* qWeo = (L & 1) ? qWe0 : qWe1;
    float* qbeo = (L & 1) ? qbe0 : qbe1;

    k_layer<<<dim3(NTOK), dim3(512), 0, stream>>>(
        qbi, kbi, vbi, qWei, qbei, edges,
        We + (size_t)L * EDGE * INNER, be + L * INNER,
        Wo + (size_t)L * INNER * DIM, bo + L * DIM,
        Wg_attn + L * 3 * DIM,
        ln2_s + L * DIM, ln2_b + L * DIM,
        W1 + (size_t)L * DIM * FFD, b1 + L * FFD,
        W2 + (size_t)L * FFD * DIM, b2 + L * DIM,
        Wg_ff + L * 3 * DIM,
        (L == 0) ? nodes : xbuf, xbuf,
        (L < DEPTH - 1) ? 1 : 0,
        ln1_s + Ln * DIM, ln1_b + Ln * DIM,
        Wq + (size_t)Ln * DIM * INNER, bq + Ln * INNER,
        Wkv + (size_t)Ln * DIM * 2 * INNER, bkv + Ln * 2 * INNER,
        We + (size_t)Ln * EDGE * INNER, be + Ln * INNER,
        cosS, sinS, qbo, kbo, vbo, qWeo, qbeo);
  }

  k_final<<<dim3(1), dim3(384), 0, stream>>>(xbuf, Wd1, bd1, Wd2, bd2, (float*)d_out);
}

// Round 13
// 131.762 us; speedup vs baseline: 1.3632x; 1.0480x over previous
//
#include <hip/hip_runtime.h>
#include <math.h>

#define NTOK 384
#define DIM  128
#define HEADS 4
#define DHEAD 64
#define INNER 256
#define DEPTH 3
#define EDGE 8
#define FFD 512

__device__ __forceinline__ float wave_sum64(float v){
#pragma unroll
  for (int m = 32; m >= 1; m >>= 1) v += __shfl_xor(v, m, 64);
  return v;
}
__device__ __forceinline__ float wave_max64(float v){
#pragma unroll
  for (int m = 32; m >= 1; m >>= 1) v = fmaxf(v, __shfl_xor(v, m, 64));
  return v;
}
// 32-lane segment reductions (for 96-thread-per-head mappings).
__device__ __forceinline__ float seg_sum32(float v){
#pragma unroll
  for (int m = 16; m >= 1; m >>= 1) v += __shfl_xor(v, m, 32);
  return v;
}
__device__ __forceinline__ float seg_max32(float v){
#pragma unroll
  for (int m = 16; m >= 1; m >>= 1) v = fmaxf(v, __shfl_xor(v, m, 32));
  return v;
}

// XCD-pinned row mapping: 384 = 8 XCDs x 48 rows.
__device__ __forceinline__ int swz_row(int id){ return (id & 7) * 48 + (id >> 3); }

// Rotary for one (i, d): numpy float32 semantics via double precision then round.
__device__ __forceinline__ void rotary_val(int i, int d, float* c, float* s){
  int j = d >> 1;
  double ex = (double)(2 * j) / 64.0;
  float p = (float)pow(10000.0, ex);
  float inv = 1.0f / p;
  float f = (float)i * inv;
  double fd = (double)f;
  *c = (float)cos(fd);
  *s = (float)sin(fd);
}

// QKV (+rotary, qWe, qbe) for ONE row. Block >= 512 threads.
// t<192 -> (quad=t, ks=0); 192<=t<384 -> (quad=t-192, ks=1).
// quad 0-63: q col-quad; 64-127: k (transposed store); 128-191: v (row-major).
// Contains 1 barrier (all threads reach it).
__device__ __forceinline__ void qkv_row_v2(
    int i, int t, const float* __restrict__ snx,
    const float* __restrict__ Wq, const float* __restrict__ bq,
    const float* __restrict__ Wkv, const float* __restrict__ bkv,
    const float* __restrict__ We, const float* __restrict__ be,
    const float* __restrict__ cosRow, const float* __restrict__ sinRow,
    float* __restrict__ qb_, float* __restrict__ kbT, float* __restrict__ vb_,
    float* __restrict__ qWeB, float* __restrict__ qbeB,
    float4* __restrict__ qp4)     // LDS, 192 float4
{
  int ks   = (t < 192) ? 0 : 1;
  int quad = (t < 192) ? t : t - 192;
  float4 acc = {0.f, 0.f, 0.f, 0.f};
  if (t < 384){
    const float4* Wp; int stride4;
    if (quad < 64){ Wp = (const float4*)Wq + quad;         stride4 = 64;  }
    else          { Wp = (const float4*)Wkv + (quad - 64); stride4 = 128; }
    int k0 = ks * 64;
#pragma unroll 8
    for (int kk = 0; kk < 64; ++kk){
      int k = k0 + kk;
      float4 w = Wp[(size_t)k * stride4];
      float x = snx[k];
      acc.x = fmaf(x, w.x, acc.x); acc.y = fmaf(x, w.y, acc.y);
      acc.z = fmaf(x, w.z, acc.z); acc.w = fmaf(x, w.w, acc.w);
    }
    if (ks == 1) qp4[quad] = acc;
  }
  __syncthreads();
  if (t < 192){
    float4 p = qp4[quad];
    acc.x += p.x; acc.y += p.y; acc.z += p.z; acc.w += p.w;
    if (quad < 64){
      int c0 = 4 * quad;
      float4 b = ((const float4*)bq)[quad];
      float a0 = acc.x + b.x, a1 = acc.y + b.y, a2 = acc.z + b.z, a3 = acc.w + b.w;
      int d0 = c0 & 63;
      float c_0 = cosRow[d0],     s_0 = sinRow[d0];
      float c_1 = cosRow[d0 + 2], s_1 = sinRow[d0 + 2];
      float r0 = a0 * c_0 - a1 * s_0;
      float r1 = a1 * c_0 + a0 * s_0;
      float r2 = a2 * c_1 - a3 * s_1;
      float r3 = a3 * c_1 + a2 * s_1;
      float4 qv; qv.x = r0; qv.y = r1; qv.z = r2; qv.w = r3;
      *(float4*)(qb_ + (size_t)i * 256 + c0) = qv;
      int h = quad >> 4;
#pragma unroll
      for (int cc = 0; cc < 8; ++cc){
        const float* wc = We + cc * 256 + c0;
        float pr = r0 * wc[0] + r1 * wc[1] + r2 * wc[2] + r3 * wc[3];
#pragma unroll
        for (int m = 8; m >= 1; m >>= 1) pr += __shfl_xor(pr, m, 16);
        if ((t & 15) == 0) qWeB[(h * NTOK + i) * 8 + cc] = pr;
      }
      const float* bc = be + c0;
      float pb = r0 * bc[0] + r1 * bc[1] + r2 * bc[2] + r3 * bc[3];
#pragma unroll
      for (int m = 8; m >= 1; m >>= 1) pb += __shfl_xor(pb, m, 16);
      if ((t & 15) == 0) qbeB[h * NTOK + i] = pb;
    } else if (quad < 128){
      int c0 = 4 * (quad - 64);
      float4 b = ((const float4*)bkv)[quad - 64];
      float a0 = acc.x + b.x, a1 = acc.y + b.y, a2 = acc.z + b.z, a3 = acc.w + b.w;
      int d0 = c0 & 63, h = c0 >> 6;
      float c_0 = cosRow[d0],     s_0 = sinRow[d0];
      float c_1 = cosRow[d0 + 2], s_1 = sinRow[d0 + 2];
      float r0 = a0 * c_0 - a1 * s_0;
      float r1 = a1 * c_0 + a0 * s_0;
      float r2 = a2 * c_1 - a3 * s_1;
      float r3 = a3 * c_1 + a2 * s_1;
      float* kp = kbT + (size_t)(h * 64 + d0) * NTOK + i;
      kp[0]        = r0;
      kp[NTOK]     = r1;
      kp[2 * NTOK] = r2;
      kp[3 * NTOK] = r3;
    } else {
      int vq = quad - 128;
      int c0 = 4 * vq;
      float4 b = ((const float4*)bkv)[64 + vq];
      float4 vv;
      vv.x = acc.x + b.x; vv.y = acc.y + b.y;
      vv.z = acc.z + b.z; vv.w = acc.w + b.w;
      *(float4*)(vb_ + (size_t)i * 256 + c0) = vv;
    }
  }
}

// Layer-0: rotary + LN1 (single wave) + QKV. 512 thr/row.
__global__ __launch_bounds__(512, 4) void k_lnqkv(
    const float* __restrict__ x,
    const float* __restrict__ ls, const float* __restrict__ lb,
    const float* __restrict__ Wq, const float* __restrict__ bq,
    const float* __restrict__ Wkv, const float* __restrict__ bkv,
    const float* __restrict__ We, const float* __restrict__ be,
    float* __restrict__ cosS, float* __restrict__ sinS,
    float* __restrict__ qb_, float* __restrict__ kbT, float* __restrict__ vb_,
    float* __restrict__ qWeB, float* __restrict__ qbeB)
{
  __shared__ float snx[128];
  __shared__ float crow[64], srow[64];
  __shared__ float4 qp4[192];
  int i = swz_row(blockIdx.x);
  int t = threadIdx.x;

  if (t >= 448){
    int d = t - 448;
    float c, s;
    rotary_val(i, d, &c, &s);
    crow[d] = c; srow[d] = s;
    cosS[i * 64 + d] = c; sinS[i * 64 + d] = s;
  }
  if (t < 64){
    float x0 = x[(size_t)i * 128 + t], x1 = x[(size_t)i * 128 + 64 + t];
    float mu = wave_sum64(x0 + x1) * (1.0f / 128.0f);
    float d0 = x0 - mu, d1 = x1 - mu;
    float var = wave_sum64(d0 * d0 + d1 * d1) * (1.0f / 128.0f);
    float rstd = 1.0f / sqrtf(var + 1e-3f);
    snx[t]      = d0 * rstd * ls[t]      + lb[t];
    snx[t + 64] = d1 * rstd * ls[t + 64] + lb[t + 64];
  }
  __syncthreads();
  qkv_row_v2(i, t, snx, Wq, bq, Wkv, bkv, We, be, crow, srow,
             qb_, kbT, vb_, qWeB, qbeB, qp4);
}

// Fused per-layer kernel: attention (4 heads) + proj + gates + LN2 + FFN
// (+ next-layer LN1 + QKV). One row per block, 512 threads, <=128 VGPR.
__global__ __launch_bounds__(512, 4) void k_layer(
    const float* __restrict__ qb_, const float* __restrict__ kbT, const float* __restrict__ vb_,
    const float* __restrict__ qWeB, const float* __restrict__ qbeB,
    const float* __restrict__ edges,
    const float* __restrict__ We, const float* __restrict__ be,    // layer L (attn epilogue)
    const float* __restrict__ Wo, const float* __restrict__ bo,
    const float* __restrict__ Wg_a,
    const float* __restrict__ ln2s, const float* __restrict__ ln2b,
    const float* __restrict__ W1, const float* __restrict__ b1,
    const float* __restrict__ W2, const float* __restrict__ b2,
    const float* __restrict__ Wg_f,
    const float* __restrict__ xin, float* __restrict__ xout,
    int has_next,
    const float* __restrict__ ls_n, const float* __restrict__ lb_n,
    const float* __restrict__ Wq_n, const float* __restrict__ bq_n,
    const float* __restrict__ Wkv_n, const float* __restrict__ bkv_n,
    const float* __restrict__ We_n, const float* __restrict__ be_n,
    const float* __restrict__ cosS, const float* __restrict__ sinS,
    float* __restrict__ qb_o, float* __restrict__ kbT_o, float* __restrict__ vb_o,
    float* __restrict__ qWeB_o, float* __restrict__ qbeB_o)
{
  __shared__ float qsL[256];
  __shared__ float qw[4][8];
  __shared__ float qbe[4];
  __shared__ __align__(16) float attnL[4][384];   // attn weights
  __shared__ float redA[12], redB[12];
  __shared__ float red8[12][8];
  __shared__ float part[512];
  __shared__ float ar[256];
  __shared__ float xold[128];
  __shared__ float xrow[128];
  __shared__ float snx[128];
  __shared__ float hs[512];
  __shared__ float4 prL[512];
  float* prF = (float*)prL;

  int i = swz_row(blockIdx.x);
  int t = threadIdx.x;

  // ---- stage q/qw/qbe/xold
  if (t < 256) qsL[t] = qb_[(size_t)i * 256 + t];
  else if (t < 288){ int idx = t - 256; qw[idx >> 3][idx & 7] = qWeB[((idx >> 3) * NTOK + i) * 8 + (idx & 7)]; }
  else if (t < 292) qbe[t - 288] = qbeB[(t - 288) * NTOK + i];
  else if (t >= 384) xold[t - 384] = xin[(size_t)i * 128 + (t - 384)];
  __syncthreads();

  // ---- sim + softmax + aw in quad ownership: t<384 -> (h = t/96, j4 = t%96)
  if (t < 384){
    int h = t / 96, j4 = t % 96;
    int j0 = 4 * j4;
    const float4* kT4 = (const float4*)(kbT + (size_t)(h * 64) * NTOK) + j4;
    const float* qsp = qsL + h * 64;
    float sA = 0.f, sB = 0.f, sC = 0.f, sD = 0.f;
#pragma unroll 16
    for (int d = 0; d < 64; ++d){
      float4 kv = kT4[(size_t)d * (NTOK / 4)];
      float q = qsp[d];
      sA = fmaf(q, kv.x, sA); sB = fmaf(q, kv.y, sB);
      sC = fmaf(q, kv.z, sC); sD = fmaf(q, kv.w, sD);
    }
    const float4* ep4 = (const float4*)(edges + ((size_t)i * NTOK + j0) * 8);
    float4 e0s[4], e1s[4];
    float ed[4];
#pragma unroll
    for (int jj = 0; jj < 4; ++jj){
      float4 e0 = ep4[2 * jj], e1 = ep4[2 * jj + 1];
      e0s[jj] = e0; e1s[jj] = e1;
      ed[jj] = e0.x * qw[h][0] + e0.y * qw[h][1] + e0.z * qw[h][2] + e0.w * qw[h][3]
             + e1.x * qw[h][4] + e1.y * qw[h][5] + e1.z * qw[h][6] + e1.w * qw[h][7];
    }
    float qbv = qbe[h];
    float s0 = 0.125f * (sA + ed[0] + qbv);
    float s1 = 0.125f * (sB + ed[1] + qbv);
    float s2 = 0.125f * (sC + ed[2] + qbv);
    float s3 = 0.125f * (sD + ed[3] + qbv);

    float mx = seg_max32(fmaxf(fmaxf(s0, s1), fmaxf(s2, s3)));
    if ((t & 31) == 0) redA[t >> 5] = mx;
    __syncthreads();
    float gm = fmaxf(fmaxf(redA[3 * h], redA[3 * h + 1]), redA[3 * h + 2]);
    float ex0 = expf(s0 - gm), ex1 = expf(s1 - gm), ex2 = expf(s2 - gm), ex3 = expf(s3 - gm);
    float sm = seg_sum32((ex0 + ex1) + (ex2 + ex3));
    if ((t & 31) == 0) redB[t >> 5] = sm;
    __syncthreads();
    float inv = 1.0f / (redB[3 * h] + redB[3 * h + 1] + redB[3 * h + 2]);
    float w0 = ex0 * inv, w1 = ex1 * inv, w2 = ex2 * inv, w3 = ex3 * inv;
    float4 wvv; wvv.x = w0; wvv.y = w1; wvv.z = w2; wvv.w = w3;
    *(float4*)&attnL[h][j0] = wvv;

    float a8[8];
    a8[0] = w0 * e0s[0].x + w1 * e0s[1].x + w2 * e0s[2].x + w3 * e0s[3].x;
    a8[1] = w0 * e0s[0].y + w1 * e0s[1].y + w2 * e0s[2].y + w3 * e0s[3].y;
    a8[2] = w0 * e0s[0].z + w1 * e0s[1].z + w2 * e0s[2].z + w3 * e0s[3].z;
    a8[3] = w0 * e0s[0].w + w1 * e0s[1].w + w2 * e0s[2].w + w3 * e0s[3].w;
    a8[4] = w0 * e1s[0].x + w1 * e1s[1].x + w2 * e1s[2].x + w3 * e1s[3].x;
    a8[5] = w0 * e1s[0].y + w1 * e1s[1].y + w2 * e1s[2].y + w3 * e1s[3].y;
    a8[6] = w0 * e1s[0].z + w1 * e1s[1].z + w2 * e1s[2].z + w3 * e1s[3].z;
    a8[7] = w0 * e1s[0].w + w1 * e1s[1].w + w2 * e1s[2].w + w3 * e1s[3].w;
#pragma unroll
    for (int cc = 0; cc < 8; ++cc){
      float r = seg_sum32(a8[cc]);
      if ((t & 31) == 0) red8[t >> 5][cc] = r;
    }
  } else {
    __syncthreads();
    __syncthreads();
  }
  __syncthreads();   // attnL + red8 ready

  // ---- PV: t -> (h, d, half); lanes = adjacent d -> coalesced 256B lines.
  // 4 independent accumulator chains for MLP.
  {
    int hh = t >> 7, dd = t & 63, half = (t >> 6) & 1;
    const float* vp = vb_ + hh * 64 + dd;
    const float* aw_ = attnL[hh];
    int j0 = half * 192;
    float a0 = 0.f, a1 = 0.f, a2 = 0.f, a3 = 0.f;
#pragma unroll 12
    for (int jj2 = 0; jj2 < 192; jj2 += 4){
      a0 = fmaf(aw_[j0 + jj2],     vp[(size_t)(j0 + jj2) * 256],     a0);
      a1 = fmaf(aw_[j0 + jj2 + 1], vp[(size_t)(j0 + jj2 + 1) * 256], a1);
      a2 = fmaf(aw_[j0 + jj2 + 2], vp[(size_t)(j0 + jj2 + 2) * 256], a2);
      a3 = fmaf(aw_[j0 + jj2 + 3], vp[(size_t)(j0 + jj2 + 3) * 256], a3);
    }
    part[t] = (a0 + a1) + (a2 + a3);
  }
  __syncthreads();
  if (t < 256){
    int h2 = t >> 6, d = t & 63;
    float o = part[h2 * 128 + d] + part[h2 * 128 + 64 + d];
    float ew = 0.f;
#pragma unroll
    for (int cc = 0; cc < 8; ++cc)
      ew = fmaf(red8[3 * h2][cc] + red8[3 * h2 + 1][cc] + red8[3 * h2 + 2][cc],
                We[cc * 256 + h2 * 64 + d], ew);
    ar[t] = o + ew + be[h2 * 64 + d];
  }
  __syncthreads();

  // ---- proj: 128 outs, K=256. 32 colq x 16 ksub.
  {
    int colq = t & 31, ksub = t >> 5;
    const float4* Wo4 = (const float4*)Wo;
    float4 acc = {0.f, 0.f, 0.f, 0.f};
#pragma unroll
    for (int kk = 0; kk < 16; ++kk){
      int k = ksub * 16 + kk;
      float4 w = Wo4[(size_t)k * 32 + colq];
      float a = ar[k];
      acc.x = fmaf(a, w.x, acc.x); acc.y = fmaf(a, w.y, acc.y);
      acc.z = fmaf(a, w.z, acc.z); acc.w = fmaf(a, w.w, acc.w);
    }
    prL[ksub * 32 + colq] = acc;
  }
  __syncthreads();

  // ---- single-wave: proj-reduce + gate_a + LN2
  if (t < 64){
    float o0 = bo[t], o1 = bo[t + 64];
#pragma unroll
    for (int s = 0; s < 16; ++s){ o0 += prF[s * 128 + t]; o1 += prF[s * 128 + 64 + t]; }
    float xo0 = xold[t], xo1 = xold[t + 64];
    float gp = o0 * Wg_a[t]      + xo0 * Wg_a[128 + t] + (o0 - xo0) * Wg_a[256 + t]
             + o1 * Wg_a[64 + t] + xo1 * Wg_a[192 + t] + (o1 - xo1) * Wg_a[320 + t];
    float z = wave_sum64(gp);
    float gg = 1.0f / (1.0f + expf(-z));
    float xr0 = o0 * gg + xo0 * (1.0f - gg);
    float xr1 = o1 * gg + xo1 * (1.0f - gg);
    xrow[t] = xr0; xrow[t + 64] = xr1;
    float mu = wave_sum64(xr0 + xr1) * (1.0f / 128.0f);
    float d0 = xr0 - mu, d1 = xr1 - mu;
    float var = wave_sum64(d0 * d0 + d1 * d1) * (1.0f / 128.0f);
    float rstd = 1.0f / sqrtf(var + 1e-3f);
    snx[t]      = d0 * rstd * ln2s[t]      + ln2b[t];
    snx[t + 64] = d1 * rstd * ln2s[t + 64] + ln2b[t + 64];
  }
  __syncthreads();

  // ---- FFN1: 512 outs, K=128. 128 colq x 4 ksub.
  {
    int colq = t & 127, ksub = t >> 7;
    const float4* W14 = (const float4*)W1;
    float4 acc = {0.f, 0.f, 0.f, 0.f};
#pragma unroll 8
    for (int kk = 0; kk < 32; ++kk){
      int k = ksub * 32 + kk;
      float4 w = W14[(size_t)k * 128 + colq];
      float a = snx[k];
      acc.x = fmaf(a, w.x, acc.x); acc.y = fmaf(a, w.y, acc.y);
      acc.z = fmaf(a, w.z, acc.z); acc.w = fmaf(a, w.w, acc.w);
    }
    prL[ksub * 128 + colq] = acc;
  }
  __syncthreads();

  // ---- GELU reduce -> hs
  {
    float hv = b1[t];
#pragma unroll
    for (int s3 = 0; s3 < 4; ++s3) hv += prF[s3 * 512 + t];
    const float RS2 = 0.70710678118654752440f;
    hs[t] = 0.5f * hv * (1.0f + erff(hv * RS2));
  }
  __syncthreads();

  // ---- FFN2: 128 outs, K=512. 32 colq x 16 ksub.
  {
    int colq = t & 31, ksub = t >> 5;
    const float4* W24 = (const float4*)W2;
    float4 acc = {0.f, 0.f, 0.f, 0.f};
#pragma unroll 8
    for (int kk = 0; kk < 32; ++kk){
      int k = ksub * 32 + kk;
      float4 w = W24[(size_t)k * 32 + colq];
      float a = hs[k];
      acc.x = fmaf(a, w.x, acc.x); acc.y = fmaf(a, w.y, acc.y);
      acc.z = fmaf(a, w.z, acc.z); acc.w = fmaf(a, w.w, acc.w);
    }
    prL[ksub * 32 + colq] = acc;
  }
  __syncthreads();

  // ---- single-wave: FFN2-reduce + gate_f + xnew + next-layer LN1
  if (t < 64){
    float f0 = b2[t], f1 = b2[t + 64];
#pragma unroll
    for (int s3 = 0; s3 < 16; ++s3){ f0 += prF[s3 * 128 + t]; f1 += prF[s3 * 128 + 64 + t]; }
    float xr0 = xrow[t], xr1 = xrow[t + 64];
    float gp = f0 * Wg_f[t]      + xr0 * Wg_f[128 + t] + (f0 - xr0) * Wg_f[256 + t]
             + f1 * Wg_f[64 + t] + xr1 * Wg_f[192 + t] + (f1 - xr1) * Wg_f[320 + t];
    float z = wave_sum64(gp);
    float gg = 1.0f / (1.0f + expf(-z));
    float xn0 = f0 * gg + xr0 * (1.0f - gg);
    float xn1 = f1 * gg + xr1 * (1.0f - gg);
    xout[(size_t)i * 128 + t]      = xn0;
    xout[(size_t)i * 128 + 64 + t] = xn1;
    if (has_next){
      float mu = wave_sum64(xn0 + xn1) * (1.0f / 128.0f);
      float d0 = xn0 - mu, d1 = xn1 - mu;
      float var = wave_sum64(d0 * d0 + d1 * d1) * (1.0f / 128.0f);
      float rstd = 1.0f / sqrtf(var + 1e-3f);
      snx[t]      = d0 * rstd * ls_n[t]      + lb_n[t];
      snx[t + 64] = d1 * rstd * ls_n[t + 64] + lb_n[t + 64];
    }
  }
  __syncthreads();

  if (has_next){
    qkv_row_v2(i, t, snx, Wq_n, bq_n, Wkv_n, bkv_n, We_n, be_n,
               cosS + (size_t)i * 64, sinS + (size_t)i * 64,
               qb_o, kbT_o, vb_o, qWeB_o, qbeB_o, prL);
  }
}

// Final head. Single block, 384 threads.
__global__ __launch_bounds__(384) void k_final(
    const float* __restrict__ x,
    const float* __restrict__ Wd1, const float* __restrict__ bd1,
    const float* __restrict__ Wd2, const float* __restrict__ bd2,
    float* __restrict__ out)
{
  __shared__ float red[6];
  int i = threadIdx.x;
  float y[9];
#pragma unroll
  for (int c = 0; c < 9; ++c) y[c] = bd1[c];
  const float4* x4 = (const float4*)(x + (size_t)i * 128);
#pragma unroll 8
  for (int r4 = 0; r4 < 32; ++r4){
    float4 xv = x4[r4];
    const float* wp = Wd1 + (r4 * 4) * 9;
#pragma unroll
    for (int c = 0; c < 9; ++c) y[c] = fmaf(xv.x, wp[c], y[c]);
#pragma unroll
    for (int c = 0; c < 9; ++c) y[c] = fmaf(xv.y, wp[9 + c], y[c]);
#pragma unroll
    for (int c = 0; c < 9; ++c) y[c] = fmaf(xv.z, wp[18 + c], y[c]);
#pragma unroll
    for (int c = 0; c < 9; ++c) y[c] = fmaf(xv.w, wp[27 + c], y[c]);
  }
#pragma unroll
  for (int c = 0; c < 9; ++c) y[c] = fmaxf(y[c], 0.0f);
  float z[3];
#pragma unroll
  for (int c = 0; c < 3; ++c){
    float a = bd2[c];
#pragma unroll
    for (int r = 0; r < 9; ++r) a = fmaf(y[r], Wd2[r * 3 + c], a);
    z[c] = a;
  }
#pragma unroll
  for (int c = 0; c < 3; ++c){
    float s = wave_sum64(z[c]);
    if ((i & 63) == 0) red[i >> 6] = s;
    __syncthreads();
    float tot = 0.f;
#pragma unroll
    for (int w = 0; w < 6; ++w) tot += red[w];
    float mean = tot * (1.0f / 384.0f);
    out[i * 3 + c] = z[c] - mean;
    __syncthreads();
  }
}

extern "C" void kernel_launch(void* const* d_in, const int* in_sizes, int n_in,
                              void* d_out, int out_size, void* d_ws, size_t ws_size,
                              hipStream_t stream)
{
  const float* nodes   = (const float*)d_in[0];
  const float* edges   = (const float*)d_in[1];
  const float* ln1_s   = (const float*)d_in[2];
  const float* ln1_b   = (const float*)d_in[3];
  const float* Wq      = (const float*)d_in[4];
  const float* bq      = (const float*)d_in[5];
  const float* Wkv     = (const float*)d_in[6];
  const float* bkv     = (const float*)d_in[7];
  const float* We      = (const float*)d_in[8];
  const float* be      = (const float*)d_in[9];
  const float* Wo      = (const float*)d_in[10];
  const float* bo      = (const float*)d_in[11];
  const float* Wg_attn = (const float*)d_in[12];
  const float* ln2_s   = (const float*)d_in[13];
  const float* ln2_b   = (const float*)d_in[14];
  const float* W1      = (const float*)d_in[15];
  const float* b1      = (const float*)d_in[16];
  const float* W2      = (const float*)d_in[17];
  const float* b2      = (const float*)d_in[18];
  const float* Wg_ff   = (const float*)d_in[19];
  const float* Wd1     = (const float*)d_in[20];
  const float* bd1     = (const float*)d_in[21];
  const float* Wd2     = (const float*)d_in[22];
  const float* bd2     = (const float*)d_in[23];
  // d_in[24] = mask: all-true; no-op in the math.

  float* ws   = (float*)d_ws;
  float* cosS = ws;                  // 384*64
  float* sinS = cosS + 24576;
  // double-buffered q/k/v sets (layer parity)
  float* qb0   = sinS + 24576;       // 384*256
  float* kbT0  = qb0 + 98304;        // [4][64][384]
  float* vb0   = kbT0 + 98304;       // row-major V
  float* qWe0  = vb0 + 98304;        // 4*384*8
  float* qbe0  = qWe0 + 12288;       // 4*384
  float* qb1   = qbe0 + 1536;
  float* kbT1  = qb1 + 98304;
  float* vb1   = kbT1 + 98304;
  float* qWe1  = vb1 + 98304;
  float* qbe1  = qWe1 + 12288;
  float* xbuf  = qbe1 + 1536;        // 384*128

  k_lnqkv<<<dim3(NTOK), dim3(512), 0, stream>>>(
      nodes, ln1_s, ln1_b, Wq, bq, Wkv, bkv, We, be,
      cosS, sinS, qb0, kbT0, vb0, qWe0, qbe0);

  for (int L = 0; L < DEPTH; ++L){
    int Ln = (L < DEPTH - 1) ? (L + 1) : L;
    const float* qbi  = (L & 1) ? qb1  : qb0;
    const float* kbi  = (L & 1) ? kbT1 : kbT0;
    const float* vbi  = (L & 1) ? vb1  : vb0;
    const float* qWei = (L & 1) ? qWe1 : qWe0;
    const float* qbei = (L & 1) ? qbe1 : qbe0;
    float* qbo  = (L & 1) ? qb0  : qb1;
    float* kbo  = (L & 1) ? kbT0 : kbT1;
    float* vbo  = (L & 1) ? vb0  : vb1;
    float* qWeo = (L & 1) ? qWe0 : qWe1;
    float* qbeo = (L & 1) ? qbe0 : qbe1;

    k_layer<<<dim3(NTOK), dim3(512), 0, stream>>>(
        qbi, kbi, vbi, qWei, qbei, edges,
        We + (size_t)L * EDGE * INNER, be + L * INNER,
        Wo + (size_t)L * INNER * DIM, bo + L * DIM,
        Wg_attn + L * 3 * DIM,
        ln2_s + L * DIM, ln2_b + L * DIM,
        W1 + (size_t)L * DIM * FFD, b1 + L * FFD,
        W2 + (size_t)L * FFD * DIM, b2 + L * DIM,
        Wg_ff + L * 3 * DIM,
        (L == 0) ? nodes : xbuf, xbuf,
        (L < DEPTH - 1) ? 1 : 0,
        ln1_s + Ln * DIM, ln1_b + Ln * DIM,
        Wq + (size_t)Ln * DIM * INNER, bq + Ln * INNER,
        Wkv + (size_t)Ln * DIM * 2 * INNER, bkv + Ln * 2 * INNER,
        We + (size_t)Ln * EDGE * INNER, be + Ln * INNER,
        cosS, sinS, qbo, kbo, vbo, qWeo, qbeo);
  }

  k_final<<<dim3(1), dim3(384), 0, stream>>>(xbuf, Wd1, bd1, Wd2, bd2, (float*)d_out);
}